// Round 19
// baseline (320.311 us; speedup 1.0000x reference)
//
#include <hip/hip_runtime.h>
#include <hip/hip_bf16.h>
#include <math.h>

#define N_NODES 50000
#define N_EDGES 800000
#define NH 4
#define ND 64
#define NF 256   // NH*ND = feature width everywhere (IN=256 too)
#define NC 16
#define NEG_SLOPE 0.2f
#define NSLICE 4      // feature slices (64 feats = 128B each = ONE HEAD); slice = blockIdx&3
#define SLICE_W 64
#define LOG2E 1.44269504088896340736f

typedef __attribute__((ext_vector_type(8))) short bf16x8;
typedef __attribute__((ext_vector_type(4))) float f32x4;

__device__ __forceinline__ float elu_f(float x) {
    return x > 0.f ? x : (__expf(x) - 1.f);
}

__device__ __forceinline__ ushort bf16_rne(float f) {
    union { float f; unsigned u; } v; v.f = f;
    unsigned u = v.u;
    u += 0x7fffu + ((u >> 16) & 1u);   // round-to-nearest-even
    return (ushort)(u >> 16);
}

__device__ __forceinline__ float bf2f(ushort u) {
    return __uint_as_float(((unsigned)u) << 16);
}

// ---------------- cast x (f32) -> bf16 ----------------
__global__ __launch_bounds__(256) void cast_bf16_kernel(const float* __restrict__ in,
                                                        ushort* __restrict__ out, int n8) {
    int i = blockIdx.x * 256 + threadIdx.x;
    if (i >= n8) return;
    float4 a = *(const float4*)(in + i * 8);
    float4 b = *(const float4*)(in + i * 8 + 4);
    ushort o[8] = {bf16_rne(a.x), bf16_rne(a.y), bf16_rne(a.z), bf16_rne(a.w),
                   bf16_rne(b.x), bf16_rne(b.y), bf16_rne(b.z), bf16_rne(b.w)};
    *(bf16x8*)(out + i * 8) = *(bf16x8*)o;
}

// ---- transpose+cast W[k][n] f32 -> Wt[n][k] bf16, two weights in one launch ----
__global__ __launch_bounds__(256) void castWt_kernel(const float* __restrict__ W0,
                                                     const float* __restrict__ W1,
                                                     ushort* __restrict__ Wt0,
                                                     ushort* __restrict__ Wt1) {
    const float* W = (blockIdx.x < 256) ? W0 : W1;
    ushort* Wt = (blockIdx.x < 256) ? Wt0 : Wt1;
    int n = blockIdx.x & 255;
    int k = threadIdx.x;
    Wt[n * 256 + k] = bf16_rne(W[k * 256 + n]);
}

// ---------------- GEMM: Cs (slice-major bf16) = A[M,256]bf16 @ Bt[n][k]bf16 ----------------
// 128x128 tile, BK=64, 256 threads (4 waves 2x2), 16x16x32 MFMA, XOR-swizzled LDS.
// Epilogue: slice-major store Cs[(col>>6)][row][col&63] + fused el/er dots
// (HEAD-MAJOR planes, pre-scaled by log2(e) so agg uses exp2 directly — exact since
// leaky_relu is positively homogeneous).
__global__ __launch_bounds__(256) void gemm_bf16(const ushort* __restrict__ A,
                                                 const ushort* __restrict__ Bt,
                                                 ushort* __restrict__ Cs,
                                                 const float* __restrict__ al,
                                                 const float* __restrict__ ar,
                                                 float* __restrict__ el,
                                                 float* __restrict__ er, int M) {
    __shared__ __align__(16) ushort As[128 * 64];   // [row][k], 16B blocks XOR-swizzled
    __shared__ __align__(16) ushort Bs[128 * 64];   // [col][k], same
    const int t = threadIdx.x;
    const int l = t & 63;
    const int w = t >> 6;
    const int wm = (w >> 1) * 64, wn = (w & 1) * 64;
    const int m0 = blockIdx.x * 128, n0 = blockIdx.y * 128;
    const int lr = l & 15, lk = l >> 4;

    f32x4 acc[4][4] = {};
    const int sr = t >> 3;            // staging row-in-issue 0..31
    const int sc = t & 7;             // global 16B-block col
    const int scw = sc ^ (sr & 7);    // swizzled LDS block

    for (int k0 = 0; k0 < 256; k0 += 64) {
        #pragma unroll
        for (int q = 0; q < 4; ++q) {
            int row = q * 32 + sr;
            int ga = min(m0 + row, M - 1);
            bf16x8 va = *(const bf16x8*)(A + (size_t)ga * 256 + k0 + sc * 8);
            *(bf16x8*)(&As[row * 64 + scw * 8]) = va;
            bf16x8 vb = *(const bf16x8*)(Bt + (size_t)(n0 + row) * 256 + k0 + sc * 8);
            *(bf16x8*)(&Bs[row * 64 + scw * 8]) = vb;
        }
        __syncthreads();
        #pragma unroll
        for (int kk = 0; kk < 2; ++kk) {
            bf16x8 af[4], bfr[4];
            #pragma unroll
            for (int mi = 0; mi < 4; ++mi) {
                int row = wm + mi * 16 + lr;
                int kb = kk * 4 + lk;
                af[mi] = *(const bf16x8*)(&As[row * 64 + (kb ^ (row & 7)) * 8]);
            }
            #pragma unroll
            for (int ni = 0; ni < 4; ++ni) {
                int col = wn + ni * 16 + lr;
                int kb = kk * 4 + lk;
                bfr[ni] = *(const bf16x8*)(&Bs[col * 64 + (kb ^ (col & 7)) * 8]);
            }
            #pragma unroll
            for (int mi = 0; mi < 4; ++mi)
                #pragma unroll
                for (int ni = 0; ni < 4; ++ni)
                    acc[mi][ni] = __builtin_amdgcn_mfma_f32_16x16x32_bf16(af[mi], bfr[ni], acc[mi][ni], 0, 0, 0);
        }
        __syncthreads();
    }
    // this wave's head and its al/ar slice (d = ni*16 + lr)
    const int h = (n0 + wn) >> 6;
    float alv[4], arv[4];
    #pragma unroll
    for (int ni = 0; ni < 4; ++ni) {
        alv[ni] = al[h * ND + ni * 16 + lr];
        arv[ni] = ar[h * ND + ni * 16 + lr];
    }
    // C/D layout: col = lane&15, row = (lane>>4)*4 + reg  [m89-verified]
    #pragma unroll
    for (int mi = 0; mi < 4; ++mi) {
        #pragma unroll
        for (int j = 0; j < 4; ++j) {
            int row = m0 + wm + mi * 16 + lk * 4 + j;
            float pe = 0.f, pr = 0.f;
            #pragma unroll
            for (int ni = 0; ni < 4; ++ni) {
                int col = n0 + wn + ni * 16 + lr;
                float v = acc[mi][ni][j];
                pe += v * alv[ni];
                pr += v * arv[ni];
                if (row < M)
                    Cs[(size_t)(col >> 6) * N_NODES * SLICE_W + (size_t)row * SLICE_W + (col & 63)] = bf16_rne(v);
            }
            #pragma unroll
            for (int m = 1; m <= 8; m <<= 1) {
                pe += __shfl_xor(pe, m, 64);
                pr += __shfl_xor(pr, m, 64);
            }
            if (lr == 0 && row < M) {
                el[h * N_NODES + row] = pe * LOG2E;   // head-major, log2e-scaled
                er[h * N_NODES + row] = pr * LOG2E;
            }
        }
    }
}

// -------- CSR build --------
__global__ __launch_bounds__(256) void hist_kernel(const int* __restrict__ dst, int* __restrict__ count) {
    int e = blockIdx.x * 256 + threadIdx.x;
    if (e < N_EDGES) atomicAdd(&count[dst[e]], 1);
}

__global__ __launch_bounds__(256) void scan1_kernel(const int* __restrict__ counts,
                                                    int* __restrict__ offs,
                                                    int* __restrict__ bsums) {
    __shared__ int sh[256];
    int tid = threadIdx.x;
    int i = blockIdx.x * 256 + tid;
    int v = (i < N_NODES) ? counts[i] : 0;
    sh[tid] = v;
    __syncthreads();
    #pragma unroll
    for (int ofs = 1; ofs < 256; ofs <<= 1) {
        int t = (tid >= ofs) ? sh[tid - ofs] : 0;
        __syncthreads();
        sh[tid] += t;
        __syncthreads();
    }
    if (i < N_NODES) offs[i] = sh[tid] - v;
    if (tid == 255) bsums[blockIdx.x] = sh[255];
}

__global__ __launch_bounds__(256) void scan2_kernel(const int* __restrict__ bsums,
                                                    int* __restrict__ boffs, int nb) {
    __shared__ int sh[256];
    int tid = threadIdx.x;
    int v = (tid < nb) ? bsums[tid] : 0;
    sh[tid] = v;
    __syncthreads();
    #pragma unroll
    for (int ofs = 1; ofs < 256; ofs <<= 1) {
        int t = (tid >= ofs) ? sh[tid - ofs] : 0;
        __syncthreads();
        sh[tid] += t;
        __syncthreads();
    }
    if (tid < nb) boffs[tid] = sh[tid] - v;
}

// scan3: finalize offs AND init cursor
__global__ __launch_bounds__(256) void scan3_kernel(int* __restrict__ offs,
                                                    const int* __restrict__ boffs,
                                                    int* __restrict__ cursor) {
    int i = blockIdx.x * 256 + threadIdx.x;
    if (i < N_NODES) {
        int v = offs[i] + boffs[i >> 8];
        offs[i] = v;
        cursor[i] = v;
    }
    if (i == 0) offs[N_NODES] = N_EDGES;
}

// scatter: store src node id per slot
__global__ __launch_bounds__(256) void scatter_kernel(const int* __restrict__ src,
                                                      const int* __restrict__ dst,
                                                      int* __restrict__ cursor,
                                                      int* __restrict__ csrc) {
    int e = blockIdx.x * 256 + threadIdx.x;
    if (e >= N_EDGES) return;
    int p = atomicAdd(&cursor[dst[e]], 1);
    csrc[p] = src[e];
}

// ======== sliced aggregation v9b: wave = 8 nodes x 1 HEAD-slice (128B granule), exp2 ========
// lane = (nn 0..7, fc 0..7): 8-lane group owns node nn's 128B slice row (fc = 16B chunk).
// Weight computed inline via exp2 (el/er pre-scaled); uniform across the 8-lane group ->
// dsum per lane IS the exact denom, no reduce, no atomics. 8-deep NAMED unroll.
// slice = blockIdx&3 -> XCD-pair pinned; 6.4MB/slice working set (L2-resident sweet spot).
#define AGG9_EDGE(K)                                                                \
        int i##K = s0 + min(t + K, degc);                                           \
        int a##K = csrc[i##K];
#define AGG9_EL(K)                                                                  \
        float e##K = elh[a##K];
#define AGG9_Q(K)                                                                   \
        bf16x8 q##K = *(const bf16x8*)(basef + a##K * SLICE_W);
#define AGG9_W(K)                                                                   \
        float x##K = e##K + ern; x##K = fmaxf(x##K, NEG_SLOPE * x##K);              \
        float w##K = (t + K < deg) ? exp2f(x##K) : 0.f;
#define AGG9_ACC(K)                                                                 \
        ac0 += w##K * bf2f((ushort)(q##K)[0]);                                      \
        ac1 += w##K * bf2f((ushort)(q##K)[1]);                                      \
        ac2 += w##K * bf2f((ushort)(q##K)[2]);                                      \
        ac3 += w##K * bf2f((ushort)(q##K)[3]);                                      \
        ac4 += w##K * bf2f((ushort)(q##K)[4]);                                      \
        ac5 += w##K * bf2f((ushort)(q##K)[5]);                                      \
        ac6 += w##K * bf2f((ushort)(q##K)[6]);                                      \
        ac7 += w##K * bf2f((ushort)(q##K)[7]);                                      \
        dsum += w##K;

#define AGG9_BODY()                                                                 \
    int b = blockIdx.x;                                                             \
    int slice = b & 3;                                                              \
    int wid = threadIdx.x >> 6;                                                     \
    int lane = threadIdx.x & 63;                                                    \
    int nn = lane >> 3;                                                             \
    int fc = lane & 7;                                                              \
    int h = slice;                                                                  \
    int n = (b >> 2) * 32 + wid * 8 + nn;                                           \
    int nc = min(n, N_NODES - 1);                                                   \
    const ushort* basef = fs + (size_t)slice * (N_NODES * SLICE_W) + fc * 8;        \
    const float* elh = el + (size_t)h * N_NODES;                                    \
    int s0 = offs[nc];                                                              \
    int deg = (n < N_NODES) ? (offs[nc + 1] - s0) : 0;                              \
    int degc = max(deg - 1, 0);                                                     \
    float ern = er[(size_t)h * N_NODES + nc];                                       \
    int md = deg;                                                                   \
    md = max(md, __shfl_xor(md, 8, 64));                                            \
    md = max(md, __shfl_xor(md, 16, 64));                                           \
    md = max(md, __shfl_xor(md, 32, 64));                                           \
    float ac0 = 0.f, ac1 = 0.f, ac2 = 0.f, ac3 = 0.f;                               \
    float ac4 = 0.f, ac5 = 0.f, ac6 = 0.f, ac7 = 0.f;                               \
    float dsum = 0.f;                                                               \
    for (int t = 0; t < md; t += 8) {                                               \
        AGG9_EDGE(0) AGG9_EDGE(1) AGG9_EDGE(2) AGG9_EDGE(3)                         \
        AGG9_EDGE(4) AGG9_EDGE(5) AGG9_EDGE(6) AGG9_EDGE(7)                         \
        AGG9_EL(0) AGG9_EL(1) AGG9_EL(2) AGG9_EL(3)                                 \
        AGG9_EL(4) AGG9_EL(5) AGG9_EL(6) AGG9_EL(7)                                 \
        AGG9_Q(0) AGG9_Q(1) AGG9_Q(2) AGG9_Q(3)                                     \
        AGG9_Q(4) AGG9_Q(5) AGG9_Q(6) AGG9_Q(7)                                     \
        AGG9_W(0) AGG9_W(1) AGG9_W(2) AGG9_W(3)                                     \
        AGG9_W(4) AGG9_W(5) AGG9_W(6) AGG9_W(7)                                     \
        AGG9_ACC(0) AGG9_ACC(1) AGG9_ACC(2) AGG9_ACC(3)                             \
        AGG9_ACC(4) AGG9_ACC(5) AGG9_ACC(6) AGG9_ACC(7)                             \
    }                                                                               \
    float inv = 1.f / fmaxf(dsum, 1e-9f);

// layer-0: write bf16 row-major hbuf (GEMM-1 A input)
__global__ __launch_bounds__(256, 8) void agg9_l0(const ushort* __restrict__ fs,
                                                  const int* __restrict__ csrc,
                                                  const int* __restrict__ offs,
                                                  const float* __restrict__ el,
                                                  const float* __restrict__ er,
                                                  ushort* __restrict__ hbuf) {
    AGG9_BODY()
    if (n < N_NODES) {
        ushort o[8] = {bf16_rne(elu_f(ac0 * inv)), bf16_rne(elu_f(ac1 * inv)),
                       bf16_rne(elu_f(ac2 * inv)), bf16_rne(elu_f(ac3 * inv)),
                       bf16_rne(elu_f(ac4 * inv)), bf16_rne(elu_f(ac5 * inv)),
                       bf16_rne(elu_f(ac6 * inv)), bf16_rne(elu_f(ac7 * inv))};
        *(bf16x8*)(hbuf + (size_t)n * NF + slice * SLICE_W + fc * 8) = *(bf16x8*)o;
    }
}

// final layer: write f32 heads into out[h][n][fc*8 .. fc*8+8)
__global__ __launch_bounds__(256, 8) void agg9_final(const ushort* __restrict__ fs,
                                                     const int* __restrict__ csrc,
                                                     const int* __restrict__ offs,
                                                     const float* __restrict__ el,
                                                     const float* __restrict__ er,
                                                     float* __restrict__ out) {
    AGG9_BODY()
    if (n < N_NODES) {
        size_t p = (size_t)h * N_NODES * (ND + NC) + (size_t)n * (ND + NC) + fc * 8;
        *(float4*)(out + p)     = make_float4(elu_f(ac0 * inv), elu_f(ac1 * inv),
                                              elu_f(ac2 * inv), elu_f(ac3 * inv));
        *(float4*)(out + p + 4) = make_float4(elu_f(ac4 * inv), elu_f(ac5 * inv),
                                              elu_f(ac6 * inv), elu_f(ac7 * inv));
    }
}

// -------- cluster softmax v2: one logit per lane (h,c), Wc in LDS --------
__global__ __launch_bounds__(256) void cluster_kernel(const float* __restrict__ Wc,
                                                      const float* __restrict__ bc,
                                                      float* __restrict__ out) {
    __shared__ float WcS[ND * NC];   // 4 KB, [d][c]
    __shared__ float bcS[NC];
    int tid = threadIdx.x;
    #pragma unroll
    for (int i = 0; i < 4; ++i) WcS[i * 256 + tid] = Wc[i * 256 + tid];
    if (tid < NC) bcS[tid] = bc[tid];
    __syncthreads();
    int wid = tid >> 6;
    int lane = tid & 63;
    int h = lane >> 4, c = lane & 15;
    int n = blockIdx.x * 4 + wid;
    size_t base = (size_t)h * N_NODES * (ND + NC) + (size_t)n * (ND + NC);
    const float* hp = out + base;
    float acc = bcS[c];
    #pragma unroll
    for (int dd = 0; dd < 16; ++dd) {
        float4 f4 = *(const float4*)(hp + dd * 4);      // same addr across 16-lane group
        acc += f4.x * WcS[(dd * 4 + 0) * NC + c];
        acc += f4.y * WcS[(dd * 4 + 1) * NC + c];
        acc += f4.z * WcS[(dd * 4 + 2) * NC + c];
        acc += f4.w * WcS[(dd * 4 + 3) * NC + c];
    }
    float m = acc;
    m = fmaxf(m, __shfl_xor(m, 1, 64));
    m = fmaxf(m, __shfl_xor(m, 2, 64));
    m = fmaxf(m, __shfl_xor(m, 4, 64));
    m = fmaxf(m, __shfl_xor(m, 8, 64));
    float e = __expf(acc - m);
    float s = e;
    s += __shfl_xor(s, 1, 64);
    s += __shfl_xor(s, 2, 64);
    s += __shfl_xor(s, 4, 64);
    s += __shfl_xor(s, 8, 64);
    out[base + ND + c] = e / s;
}

extern "C" void kernel_launch(void* const* d_in, const int* in_sizes, int n_in,
                              void* d_out, int out_size, void* d_ws, size_t ws_size,
                              hipStream_t stream) {
    const float* x   = (const float*)d_in[0];
    const int* src   = (const int*)d_in[1];
    const int* dst   = (const int*)d_in[2];
    const float* W0  = (const float*)d_in[3];
    const float* al0 = (const float*)d_in[4];
    const float* ar0 = (const float*)d_in[5];
    const float* W1  = (const float*)d_in[6];
    const float* al1 = (const float*)d_in[7];
    const float* ar1 = (const float*)d_in[8];
    const float* Wc  = (const float*)d_in[9];
    const float* bc  = (const float*)d_in[10];
    float* out = (float*)d_out;

    char* ws = (char*)d_ws;
    size_t off = 0;
    auto alloc = [&](size_t bytes) { void* p = ws + off; off = (off + bytes + 255) & ~(size_t)255; return p; };
    ushort* featsl = (ushort*)alloc((size_t)N_NODES * NF * 2);   // 25.6 MB slice-major GEMM out
    ushort* xbf    = (ushort*)alloc((size_t)N_NODES * NF * 2);   // 25.6 MB
    ushort* hbuf   = (ushort*)alloc((size_t)N_NODES * NF * 2);   // 25.6 MB layer0 out (row-major)
    ushort* Wt0    = (ushort*)alloc((size_t)256 * 256 * 2);
    ushort* Wt1    = (ushort*)alloc((size_t)256 * 256 * 2);
    float*  el     = (float*)alloc((size_t)N_NODES * NH * 4);    // head-major, log2e-scaled
    float*  er     = (float*)alloc((size_t)N_NODES * NH * 4);
    int* counts    = (int*)alloc((size_t)N_NODES * 4);
    int* offs      = (int*)alloc((size_t)(N_NODES + 1) * 4);
    int* cursor    = (int*)alloc((size_t)N_NODES * 4);
    int* csrc      = (int*)alloc((size_t)N_EDGES * 4);
    int* bsums     = (int*)alloc(256 * 4);
    int* boffs     = (int*)alloc(256 * 4);

    const int EB = (N_EDGES + 255) / 256;          // 3125
    const int NB = (N_NODES + 255) / 256;          // 196
    const int GEMM_MB = (N_NODES + 127) / 128;     // 391
    const int C8 = (N_NODES * NF / 8 + 255) / 256;
    const int AGG_B = NSLICE * ((N_NODES + 31) / 32);  // 4 * 1563 = 6252 blocks

    // ---- CSR build ----
    hipMemsetAsync(counts, 0, (size_t)N_NODES * 4, stream);
    hist_kernel<<<EB, 256, 0, stream>>>(dst, counts);
    scan1_kernel<<<NB, 256, 0, stream>>>(counts, offs, bsums);
    scan2_kernel<<<1, 256, 0, stream>>>(bsums, boffs, NB);
    scan3_kernel<<<NB, 256, 0, stream>>>(offs, boffs, cursor);
    scatter_kernel<<<EB, 256, 0, stream>>>(src, dst, cursor, csrc);

    // ---- weight + input casts ----
    castWt_kernel<<<512, 256, 0, stream>>>(W0, W1, Wt0, Wt1);
    cast_bf16_kernel<<<C8, 256, 0, stream>>>(x, xbf, N_NODES * NF / 8);

    // ---- Layer 0 ----
    gemm_bf16<<<dim3(GEMM_MB, 2), 256, 0, stream>>>(xbf, Wt0, featsl, al0, ar0, el, er, N_NODES);
    agg9_l0<<<AGG_B, 256, 0, stream>>>(featsl, csrc, offs, el, er, hbuf);

    // ---- Layer 1 ----
    gemm_bf16<<<dim3(GEMM_MB, 2), 256, 0, stream>>>(hbuf, Wt1, featsl, al1, ar1, el, er, N_NODES);
    agg9_final<<<AGG_B, 256, 0, stream>>>(featsl, csrc, offs, el, er, out);

    // ---- cluster softmax ----
    cluster_kernel<<<N_NODES / 4, 256, 0, stream>>>(Wc, bc, out);
}

// Round 20
// 317.503 us; speedup vs baseline: 1.0088x; 1.0088x over previous
//
#include <hip/hip_runtime.h>
#include <hip/hip_bf16.h>
#include <math.h>

#define N_NODES 50000
#define N_EDGES 800000
#define NH 4
#define ND 64
#define NF 256   // NH*ND = feature width everywhere (IN=256 too)
#define NC 16
#define NEG_SLOPE 0.2f
#define NSLICE 4      // feature slices (64 feats = 128B each = ONE HEAD); slice = blockIdx&3
#define SLICE_W 64
#define LOG2E 1.44269504088896340736f

typedef __attribute__((ext_vector_type(8))) short bf16x8;
typedef __attribute__((ext_vector_type(4))) float f32x4;

__device__ __forceinline__ float elu_f(float x) {
    return x > 0.f ? x : (__expf(x) - 1.f);
}

__device__ __forceinline__ ushort bf16_rne(float f) {
    union { float f; unsigned u; } v; v.f = f;
    unsigned u = v.u;
    u += 0x7fffu + ((u >> 16) & 1u);   // round-to-nearest-even
    return (ushort)(u >> 16);
}

__device__ __forceinline__ float bf2f(ushort u) {
    return __uint_as_float(((unsigned)u) << 16);
}

// ---------------- cast x (f32) -> bf16 ----------------
__global__ __launch_bounds__(256) void cast_bf16_kernel(const float* __restrict__ in,
                                                        ushort* __restrict__ out, int n8) {
    int i = blockIdx.x * 256 + threadIdx.x;
    if (i >= n8) return;
    float4 a = *(const float4*)(in + i * 8);
    float4 b = *(const float4*)(in + i * 8 + 4);
    ushort o[8] = {bf16_rne(a.x), bf16_rne(a.y), bf16_rne(a.z), bf16_rne(a.w),
                   bf16_rne(b.x), bf16_rne(b.y), bf16_rne(b.z), bf16_rne(b.w)};
    *(bf16x8*)(out + i * 8) = *(bf16x8*)o;
}

// ---- transpose+cast W[k][n] f32 -> Wt[n][k] bf16, two weights in one launch ----
__global__ __launch_bounds__(256) void castWt_kernel(const float* __restrict__ W0,
                                                     const float* __restrict__ W1,
                                                     ushort* __restrict__ Wt0,
                                                     ushort* __restrict__ Wt1) {
    const float* W = (blockIdx.x < 256) ? W0 : W1;
    ushort* Wt = (blockIdx.x < 256) ? Wt0 : Wt1;
    int n = blockIdx.x & 255;
    int k = threadIdx.x;
    Wt[n * 256 + k] = bf16_rne(W[k * 256 + n]);
}

// ---------------- GEMM: Cs (slice-major bf16) = A[M,256]bf16 @ Bt[n][k]bf16 ----------------
// 128x128 tile, BK=64, 256 threads (4 waves 2x2), 16x16x32 MFMA, XOR-swizzled LDS.
// Epilogue: slice-major store Cs[(col>>6)][row][col&63] + fused el/er dots
// (HEAD-MAJOR planes, pre-scaled by log2(e) so agg uses exp2 directly — exact since
// leaky_relu is positively homogeneous).
__global__ __launch_bounds__(256) void gemm_bf16(const ushort* __restrict__ A,
                                                 const ushort* __restrict__ Bt,
                                                 ushort* __restrict__ Cs,
                                                 const float* __restrict__ al,
                                                 const float* __restrict__ ar,
                                                 float* __restrict__ el,
                                                 float* __restrict__ er, int M) {
    __shared__ __align__(16) ushort As[128 * 64];   // [row][k], 16B blocks XOR-swizzled
    __shared__ __align__(16) ushort Bs[128 * 64];   // [col][k], same
    const int t = threadIdx.x;
    const int l = t & 63;
    const int w = t >> 6;
    const int wm = (w >> 1) * 64, wn = (w & 1) * 64;
    const int m0 = blockIdx.x * 128, n0 = blockIdx.y * 128;
    const int lr = l & 15, lk = l >> 4;

    f32x4 acc[4][4] = {};
    const int sr = t >> 3;            // staging row-in-issue 0..31
    const int sc = t & 7;             // global 16B-block col
    const int scw = sc ^ (sr & 7);    // swizzled LDS block

    for (int k0 = 0; k0 < 256; k0 += 64) {
        #pragma unroll
        for (int q = 0; q < 4; ++q) {
            int row = q * 32 + sr;
            int ga = min(m0 + row, M - 1);
            bf16x8 va = *(const bf16x8*)(A + (size_t)ga * 256 + k0 + sc * 8);
            *(bf16x8*)(&As[row * 64 + scw * 8]) = va;
            bf16x8 vb = *(const bf16x8*)(Bt + (size_t)(n0 + row) * 256 + k0 + sc * 8);
            *(bf16x8*)(&Bs[row * 64 + scw * 8]) = vb;
        }
        __syncthreads();
        #pragma unroll
        for (int kk = 0; kk < 2; ++kk) {
            bf16x8 af[4], bfr[4];
            #pragma unroll
            for (int mi = 0; mi < 4; ++mi) {
                int row = wm + mi * 16 + lr;
                int kb = kk * 4 + lk;
                af[mi] = *(const bf16x8*)(&As[row * 64 + (kb ^ (row & 7)) * 8]);
            }
            #pragma unroll
            for (int ni = 0; ni < 4; ++ni) {
                int col = wn + ni * 16 + lr;
                int kb = kk * 4 + lk;
                bfr[ni] = *(const bf16x8*)(&Bs[col * 64 + (kb ^ (col & 7)) * 8]);
            }
            #pragma unroll
            for (int mi = 0; mi < 4; ++mi)
                #pragma unroll
                for (int ni = 0; ni < 4; ++ni)
                    acc[mi][ni] = __builtin_amdgcn_mfma_f32_16x16x32_bf16(af[mi], bfr[ni], acc[mi][ni], 0, 0, 0);
        }
        __syncthreads();
    }
    // this wave's head and its al/ar slice (d = ni*16 + lr)
    const int h = (n0 + wn) >> 6;
    float alv[4], arv[4];
    #pragma unroll
    for (int ni = 0; ni < 4; ++ni) {
        alv[ni] = al[h * ND + ni * 16 + lr];
        arv[ni] = ar[h * ND + ni * 16 + lr];
    }
    // C/D layout: col = lane&15, row = (lane>>4)*4 + reg  [m89-verified]
    #pragma unroll
    for (int mi = 0; mi < 4; ++mi) {
        #pragma unroll
        for (int j = 0; j < 4; ++j) {
            int row = m0 + wm + mi * 16 + lk * 4 + j;
            float pe = 0.f, pr = 0.f;
            #pragma unroll
            for (int ni = 0; ni < 4; ++ni) {
                int col = n0 + wn + ni * 16 + lr;
                float v = acc[mi][ni][j];
                pe += v * alv[ni];
                pr += v * arv[ni];
                if (row < M)
                    Cs[(size_t)(col >> 6) * N_NODES * SLICE_W + (size_t)row * SLICE_W + (col & 63)] = bf16_rne(v);
            }
            #pragma unroll
            for (int m = 1; m <= 8; m <<= 1) {
                pe += __shfl_xor(pe, m, 64);
                pr += __shfl_xor(pr, m, 64);
            }
            if (lr == 0 && row < M) {
                el[h * N_NODES + row] = pe * LOG2E;   // head-major, log2e-scaled
                er[h * N_NODES + row] = pr * LOG2E;
            }
        }
    }
}

// -------- CSR build --------
__global__ __launch_bounds__(256) void hist_kernel(const int* __restrict__ dst, int* __restrict__ count) {
    int e = blockIdx.x * 256 + threadIdx.x;
    if (e < N_EDGES) atomicAdd(&count[dst[e]], 1);
}

__global__ __launch_bounds__(256) void scan1_kernel(const int* __restrict__ counts,
                                                    int* __restrict__ offs,
                                                    int* __restrict__ bsums) {
    __shared__ int sh[256];
    int tid = threadIdx.x;
    int i = blockIdx.x * 256 + tid;
    int v = (i < N_NODES) ? counts[i] : 0;
    sh[tid] = v;
    __syncthreads();
    #pragma unroll
    for (int ofs = 1; ofs < 256; ofs <<= 1) {
        int t = (tid >= ofs) ? sh[tid - ofs] : 0;
        __syncthreads();
        sh[tid] += t;
        __syncthreads();
    }
    if (i < N_NODES) offs[i] = sh[tid] - v;
    if (tid == 255) bsums[blockIdx.x] = sh[255];
}

__global__ __launch_bounds__(256) void scan2_kernel(const int* __restrict__ bsums,
                                                    int* __restrict__ boffs, int nb) {
    __shared__ int sh[256];
    int tid = threadIdx.x;
    int v = (tid < nb) ? bsums[tid] : 0;
    sh[tid] = v;
    __syncthreads();
    #pragma unroll
    for (int ofs = 1; ofs < 256; ofs <<= 1) {
        int t = (tid >= ofs) ? sh[tid - ofs] : 0;
        __syncthreads();
        sh[tid] += t;
        __syncthreads();
    }
    if (tid < nb) boffs[tid] = sh[tid] - v;
}

// scan3: finalize offs AND init cursor
__global__ __launch_bounds__(256) void scan3_kernel(int* __restrict__ offs,
                                                    const int* __restrict__ boffs,
                                                    int* __restrict__ cursor) {
    int i = blockIdx.x * 256 + threadIdx.x;
    if (i < N_NODES) {
        int v = offs[i] + boffs[i >> 8];
        offs[i] = v;
        cursor[i] = v;
    }
    if (i == 0) offs[N_NODES] = N_EDGES;
}

// scatter: store src node id per slot
__global__ __launch_bounds__(256) void scatter_kernel(const int* __restrict__ src,
                                                      const int* __restrict__ dst,
                                                      int* __restrict__ cursor,
                                                      int* __restrict__ csrc) {
    int e = blockIdx.x * 256 + threadIdx.x;
    if (e >= N_EDGES) return;
    int p = atomicAdd(&cursor[dst[e]], 1);
    csrc[p] = src[e];
}

// ======== sliced aggregation v9c: wave = 8 nodes x 1 HEAD-slice (128B granule), exp2 ========
// lane = (nn 0..7, fc 0..7): 8-lane group owns node nn's 128B slice row (fc = 16B chunk).
// Weight computed inline via exp2 (el/er pre-scaled); uniform across the 8-lane group ->
// dsum per lane IS the exact denom, no reduce, no atomics. 8-deep NAMED unroll.
// slice = blockIdx&3 -> XCD-pair pinned; 6.4MB/slice (L2-resident sweet spot, r17/r18).
// NO min-waves launch_bounds: VGPR 52 / ILP beats occupancy here (r19 lesson).
#define AGG9_EDGE(K)                                                                \
        int i##K = s0 + min(t + K, degc);                                           \
        int a##K = csrc[i##K];
#define AGG9_EL(K)                                                                  \
        float e##K = elh[a##K];
#define AGG9_Q(K)                                                                   \
        bf16x8 q##K = *(const bf16x8*)(basef + a##K * SLICE_W);
#define AGG9_W(K)                                                                   \
        float x##K = e##K + ern; x##K = fmaxf(x##K, NEG_SLOPE * x##K);              \
        float w##K = (t + K < deg) ? exp2f(x##K) : 0.f;
#define AGG9_ACC(K)                                                                 \
        ac0 += w##K * bf2f((ushort)(q##K)[0]);                                      \
        ac1 += w##K * bf2f((ushort)(q##K)[1]);                                      \
        ac2 += w##K * bf2f((ushort)(q##K)[2]);                                      \
        ac3 += w##K * bf2f((ushort)(q##K)[3]);                                      \
        ac4 += w##K * bf2f((ushort)(q##K)[4]);                                      \
        ac5 += w##K * bf2f((ushort)(q##K)[5]);                                      \
        ac6 += w##K * bf2f((ushort)(q##K)[6]);                                      \
        ac7 += w##K * bf2f((ushort)(q##K)[7]);                                      \
        dsum += w##K;

#define AGG9_BODY()                                                                 \
    int b = blockIdx.x;                                                             \
    int slice = b & 3;                                                              \
    int wid = threadIdx.x >> 6;                                                     \
    int lane = threadIdx.x & 63;                                                    \
    int nn = lane >> 3;                                                             \
    int fc = lane & 7;                                                              \
    int h = slice;                                                                  \
    int n = (b >> 2) * 32 + wid * 8 + nn;                                           \
    int nc = min(n, N_NODES - 1);                                                   \
    const ushort* basef = fs + (size_t)slice * (N_NODES * SLICE_W) + fc * 8;        \
    const float* elh = el + (size_t)h * N_NODES;                                    \
    int s0 = offs[nc];                                                              \
    int deg = (n < N_NODES) ? (offs[nc + 1] - s0) : 0;                              \
    int degc = max(deg - 1, 0);                                                     \
    float ern = er[(size_t)h * N_NODES + nc];                                       \
    int md = deg;                                                                   \
    md = max(md, __shfl_xor(md, 8, 64));                                            \
    md = max(md, __shfl_xor(md, 16, 64));                                           \
    md = max(md, __shfl_xor(md, 32, 64));                                           \
    float ac0 = 0.f, ac1 = 0.f, ac2 = 0.f, ac3 = 0.f;                               \
    float ac4 = 0.f, ac5 = 0.f, ac6 = 0.f, ac7 = 0.f;                               \
    float dsum = 0.f;                                                               \
    for (int t = 0; t < md; t += 8) {                                               \
        AGG9_EDGE(0) AGG9_EDGE(1) AGG9_EDGE(2) AGG9_EDGE(3)                         \
        AGG9_EDGE(4) AGG9_EDGE(5) AGG9_EDGE(6) AGG9_EDGE(7)                         \
        AGG9_EL(0) AGG9_EL(1) AGG9_EL(2) AGG9_EL(3)                                 \
        AGG9_EL(4) AGG9_EL(5) AGG9_EL(6) AGG9_EL(7)                                 \
        AGG9_Q(0) AGG9_Q(1) AGG9_Q(2) AGG9_Q(3)                                     \
        AGG9_Q(4) AGG9_Q(5) AGG9_Q(6) AGG9_Q(7)                                     \
        AGG9_W(0) AGG9_W(1) AGG9_W(2) AGG9_W(3)                                     \
        AGG9_W(4) AGG9_W(5) AGG9_W(6) AGG9_W(7)                                     \
        AGG9_ACC(0) AGG9_ACC(1) AGG9_ACC(2) AGG9_ACC(3)                             \
        AGG9_ACC(4) AGG9_ACC(5) AGG9_ACC(6) AGG9_ACC(7)                             \
    }                                                                               \
    float inv = 1.f / fmaxf(dsum, 1e-9f);

// layer-0: write bf16 row-major hbuf (GEMM-1 A input)
__global__ __launch_bounds__(256) void agg9_l0(const ushort* __restrict__ fs,
                                               const int* __restrict__ csrc,
                                               const int* __restrict__ offs,
                                               const float* __restrict__ el,
                                               const float* __restrict__ er,
                                               ushort* __restrict__ hbuf) {
    AGG9_BODY()
    if (n < N_NODES) {
        ushort o[8] = {bf16_rne(elu_f(ac0 * inv)), bf16_rne(elu_f(ac1 * inv)),
                       bf16_rne(elu_f(ac2 * inv)), bf16_rne(elu_f(ac3 * inv)),
                       bf16_rne(elu_f(ac4 * inv)), bf16_rne(elu_f(ac5 * inv)),
                       bf16_rne(elu_f(ac6 * inv)), bf16_rne(elu_f(ac7 * inv))};
        *(bf16x8*)(hbuf + (size_t)n * NF + slice * SLICE_W + fc * 8) = *(bf16x8*)o;
    }
}

// final layer: write f32 heads into out[h][n][fc*8 .. fc*8+8)
__global__ __launch_bounds__(256) void agg9_final(const ushort* __restrict__ fs,
                                                  const int* __restrict__ csrc,
                                                  const int* __restrict__ offs,
                                                  const float* __restrict__ el,
                                                  const float* __restrict__ er,
                                                  float* __restrict__ out) {
    AGG9_BODY()
    if (n < N_NODES) {
        size_t p = (size_t)h * N_NODES * (ND + NC) + (size_t)n * (ND + NC) + fc * 8;
        *(float4*)(out + p)     = make_float4(elu_f(ac0 * inv), elu_f(ac1 * inv),
                                              elu_f(ac2 * inv), elu_f(ac3 * inv));
        *(float4*)(out + p + 4) = make_float4(elu_f(ac4 * inv), elu_f(ac5 * inv),
                                              elu_f(ac6 * inv), elu_f(ac7 * inv));
    }
}

// -------- cluster softmax v2: one logit per lane (h,c), Wc in LDS --------
__global__ __launch_bounds__(256) void cluster_kernel(const float* __restrict__ Wc,
                                                      const float* __restrict__ bc,
                                                      float* __restrict__ out) {
    __shared__ float WcS[ND * NC];   // 4 KB, [d][c]
    __shared__ float bcS[NC];
    int tid = threadIdx.x;
    #pragma unroll
    for (int i = 0; i < 4; ++i) WcS[i * 256 + tid] = Wc[i * 256 + tid];
    if (tid < NC) bcS[tid] = bc[tid];
    __syncthreads();
    int wid = tid >> 6;
    int lane = tid & 63;
    int h = lane >> 4, c = lane & 15;
    int n = blockIdx.x * 4 + wid;
    size_t base = (size_t)h * N_NODES * (ND + NC) + (size_t)n * (ND + NC);
    const float* hp = out + base;
    float acc = bcS[c];
    #pragma unroll
    for (int dd = 0; dd < 16; ++dd) {
        float4 f4 = *(const float4*)(hp + dd * 4);      // same addr across 16-lane group
        acc += f4.x * WcS[(dd * 4 + 0) * NC + c];
        acc += f4.y * WcS[(dd * 4 + 1) * NC + c];
        acc += f4.z * WcS[(dd * 4 + 2) * NC + c];
        acc += f4.w * WcS[(dd * 4 + 3) * NC + c];
    }
    float m = acc;
    m = fmaxf(m, __shfl_xor(m, 1, 64));
    m = fmaxf(m, __shfl_xor(m, 2, 64));
    m = fmaxf(m, __shfl_xor(m, 4, 64));
    m = fmaxf(m, __shfl_xor(m, 8, 64));
    float e = __expf(acc - m);
    float s = e;
    s += __shfl_xor(s, 1, 64);
    s += __shfl_xor(s, 2, 64);
    s += __shfl_xor(s, 4, 64);
    s += __shfl_xor(s, 8, 64);
    out[base + ND + c] = e / s;
}

extern "C" void kernel_launch(void* const* d_in, const int* in_sizes, int n_in,
                              void* d_out, int out_size, void* d_ws, size_t ws_size,
                              hipStream_t stream) {
    const float* x   = (const float*)d_in[0];
    const int* src   = (const int*)d_in[1];
    const int* dst   = (const int*)d_in[2];
    const float* W0  = (const float*)d_in[3];
    const float* al0 = (const float*)d_in[4];
    const float* ar0 = (const float*)d_in[5];
    const float* W1  = (const float*)d_in[6];
    const float* al1 = (const float*)d_in[7];
    const float* ar1 = (const float*)d_in[8];
    const float* Wc  = (const float*)d_in[9];
    const float* bc  = (const float*)d_in[10];
    float* out = (float*)d_out;

    char* ws = (char*)d_ws;
    size_t off = 0;
    auto alloc = [&](size_t bytes) { void* p = ws + off; off = (off + bytes + 255) & ~(size_t)255; return p; };
    ushort* featsl = (ushort*)alloc((size_t)N_NODES * NF * 2);   // 25.6 MB slice-major GEMM out
    ushort* xbf    = (ushort*)alloc((size_t)N_NODES * NF * 2);   // 25.6 MB
    ushort* hbuf   = (ushort*)alloc((size_t)N_NODES * NF * 2);   // 25.6 MB layer0 out (row-major)
    ushort* Wt0    = (ushort*)alloc((size_t)256 * 256 * 2);
    ushort* Wt1    = (ushort*)alloc((size_t)256 * 256 * 2);
    float*  el     = (float*)alloc((size_t)N_NODES * NH * 4);    // head-major, log2e-scaled
    float*  er     = (float*)alloc((size_t)N_NODES * NH * 4);
    int* counts    = (int*)alloc((size_t)N_NODES * 4);
    int* offs      = (int*)alloc((size_t)(N_NODES + 1) * 4);
    int* cursor    = (int*)alloc((size_t)N_NODES * 4);
    int* csrc      = (int*)alloc((size_t)N_EDGES * 4);
    int* bsums     = (int*)alloc(256 * 4);
    int* boffs     = (int*)alloc(256 * 4);

    const int EB = (N_EDGES + 255) / 256;          // 3125
    const int NB = (N_NODES + 255) / 256;          // 196
    const int GEMM_MB = (N_NODES + 127) / 128;     // 391
    const int C8 = (N_NODES * NF / 8 + 255) / 256;
    const int AGG_B = NSLICE * ((N_NODES + 31) / 32);  // 4 * 1563 = 6252 blocks

    // ---- CSR build ----
    hipMemsetAsync(counts, 0, (size_t)N_NODES * 4, stream);
    hist_kernel<<<EB, 256, 0, stream>>>(dst, counts);
    scan1_kernel<<<NB, 256, 0, stream>>>(counts, offs, bsums);
    scan2_kernel<<<1, 256, 0, stream>>>(bsums, boffs, NB);
    scan3_kernel<<<NB, 256, 0, stream>>>(offs, boffs, cursor);
    scatter_kernel<<<EB, 256, 0, stream>>>(src, dst, cursor, csrc);

    // ---- weight + input casts ----
    castWt_kernel<<<512, 256, 0, stream>>>(W0, W1, Wt0, Wt1);
    cast_bf16_kernel<<<C8, 256, 0, stream>>>(x, xbf, N_NODES * NF / 8);

    // ---- Layer 0 ----
    gemm_bf16<<<dim3(GEMM_MB, 2), 256, 0, stream>>>(xbf, Wt0, featsl, al0, ar0, el, er, N_NODES);
    agg9_l0<<<AGG_B, 256, 0, stream>>>(featsl, csrc, offs, el, er, hbuf);

    // ---- Layer 1 ----
    gemm_bf16<<<dim3(GEMM_MB, 2), 256, 0, stream>>>(hbuf, Wt1, featsl, al1, ar1, el, er, N_NODES);
    agg9_final<<<AGG_B, 256, 0, stream>>>(featsl, csrc, offs, el, er, out);

    // ---- cluster softmax ----
    cluster_kernel<<<N_NODES / 4, 256, 0, stream>>>(Wc, bc, out);
}

// Round 21
// 306.052 us; speedup vs baseline: 1.0466x; 1.0374x over previous
//
#include <hip/hip_runtime.h>
#include <hip/hip_bf16.h>
#include <math.h>

#define N_NODES 50000
#define N_EDGES 800000
#define NH 4
#define ND 64
#define NF 256   // NH*ND = feature width everywhere (IN=256 too)
#define NC 16
#define NEG_SLOPE 0.2f
#define NSLICE 4      // feature slices (64 feats = 128B each = ONE HEAD); slice = blockIdx&3
#define SLICE_W 64

typedef __attribute__((ext_vector_type(8))) short bf16x8;
typedef __attribute__((ext_vector_type(4))) float f32x4;

__device__ __forceinline__ float elu_f(float x) {
    return x > 0.f ? x : (__expf(x) - 1.f);
}

__device__ __forceinline__ ushort bf16_rne(float f) {
    union { float f; unsigned u; } v; v.f = f;
    unsigned u = v.u;
    u += 0x7fffu + ((u >> 16) & 1u);   // round-to-nearest-even
    return (ushort)(u >> 16);
}

__device__ __forceinline__ float bf2f(ushort u) {
    return __uint_as_float(((unsigned)u) << 16);
}

// ---------------- cast x (f32) -> bf16 ----------------
__global__ __launch_bounds__(256) void cast_bf16_kernel(const float* __restrict__ in,
                                                        ushort* __restrict__ out, int n8) {
    int i = blockIdx.x * 256 + threadIdx.x;
    if (i >= n8) return;
    float4 a = *(const float4*)(in + i * 8);
    float4 b = *(const float4*)(in + i * 8 + 4);
    ushort o[8] = {bf16_rne(a.x), bf16_rne(a.y), bf16_rne(a.z), bf16_rne(a.w),
                   bf16_rne(b.x), bf16_rne(b.y), bf16_rne(b.z), bf16_rne(b.w)};
    *(bf16x8*)(out + i * 8) = *(bf16x8*)o;
}

// ---- transpose+cast W[k][n] f32 -> Wt[n][k] bf16, two weights in one launch ----
__global__ __launch_bounds__(256) void castWt_kernel(const float* __restrict__ W0,
                                                     const float* __restrict__ W1,
                                                     ushort* __restrict__ Wt0,
                                                     ushort* __restrict__ Wt1) {
    const float* W = (blockIdx.x < 256) ? W0 : W1;
    ushort* Wt = (blockIdx.x < 256) ? Wt0 : Wt1;
    int n = blockIdx.x & 255;
    int k = threadIdx.x;
    Wt[n * 256 + k] = bf16_rne(W[k * 256 + n]);
}

// ---------------- GEMM: Cs (slice-major bf16) = A[M,256]bf16 @ Bt[n][k]bf16 ----------------
// 128x128 tile, BK=64, 256 threads (4 waves 2x2), 16x16x32 MFMA, XOR-swizzled LDS.
// Epilogue: slice-major store Cs[(col>>6)][row][col&63] + fused el/er dots (HEAD-MAJOR planes).
__global__ __launch_bounds__(256) void gemm_bf16(const ushort* __restrict__ A,
                                                 const ushort* __restrict__ Bt,
                                                 ushort* __restrict__ Cs,
                                                 const float* __restrict__ al,
                                                 const float* __restrict__ ar,
                                                 float* __restrict__ el,
                                                 float* __restrict__ er, int M) {
    __shared__ __align__(16) ushort As[128 * 64];   // [row][k], 16B blocks XOR-swizzled
    __shared__ __align__(16) ushort Bs[128 * 64];   // [col][k], same
    const int t = threadIdx.x;
    const int l = t & 63;
    const int w = t >> 6;
    const int wm = (w >> 1) * 64, wn = (w & 1) * 64;
    const int m0 = blockIdx.x * 128, n0 = blockIdx.y * 128;
    const int lr = l & 15, lk = l >> 4;

    f32x4 acc[4][4] = {};
    const int sr = t >> 3;            // staging row-in-issue 0..31
    const int sc = t & 7;             // global 16B-block col
    const int scw = sc ^ (sr & 7);    // swizzled LDS block

    for (int k0 = 0; k0 < 256; k0 += 64) {
        #pragma unroll
        for (int q = 0; q < 4; ++q) {
            int row = q * 32 + sr;
            int ga = min(m0 + row, M - 1);
            bf16x8 va = *(const bf16x8*)(A + (size_t)ga * 256 + k0 + sc * 8);
            *(bf16x8*)(&As[row * 64 + scw * 8]) = va;
            bf16x8 vb = *(const bf16x8*)(Bt + (size_t)(n0 + row) * 256 + k0 + sc * 8);
            *(bf16x8*)(&Bs[row * 64 + scw * 8]) = vb;
        }
        __syncthreads();
        #pragma unroll
        for (int kk = 0; kk < 2; ++kk) {
            bf16x8 af[4], bfr[4];
            #pragma unroll
            for (int mi = 0; mi < 4; ++mi) {
                int row = wm + mi * 16 + lr;
                int kb = kk * 4 + lk;
                af[mi] = *(const bf16x8*)(&As[row * 64 + (kb ^ (row & 7)) * 8]);
            }
            #pragma unroll
            for (int ni = 0; ni < 4; ++ni) {
                int col = wn + ni * 16 + lr;
                int kb = kk * 4 + lk;
                bfr[ni] = *(const bf16x8*)(&Bs[col * 64 + (kb ^ (col & 7)) * 8]);
            }
            #pragma unroll
            for (int mi = 0; mi < 4; ++mi)
                #pragma unroll
                for (int ni = 0; ni < 4; ++ni)
                    acc[mi][ni] = __builtin_amdgcn_mfma_f32_16x16x32_bf16(af[mi], bfr[ni], acc[mi][ni], 0, 0, 0);
        }
        __syncthreads();
    }
    // this wave's head and its al/ar slice (d = ni*16 + lr)
    const int h = (n0 + wn) >> 6;
    float alv[4], arv[4];
    #pragma unroll
    for (int ni = 0; ni < 4; ++ni) {
        alv[ni] = al[h * ND + ni * 16 + lr];
        arv[ni] = ar[h * ND + ni * 16 + lr];
    }
    // C/D layout: col = lane&15, row = (lane>>4)*4 + reg  [m89-verified]
    #pragma unroll
    for (int mi = 0; mi < 4; ++mi) {
        #pragma unroll
        for (int j = 0; j < 4; ++j) {
            int row = m0 + wm + mi * 16 + lk * 4 + j;
            float pe = 0.f, pr = 0.f;
            #pragma unroll
            for (int ni = 0; ni < 4; ++ni) {
                int col = n0 + wn + ni * 16 + lr;
                float v = acc[mi][ni][j];
                pe += v * alv[ni];
                pr += v * arv[ni];
                if (row < M)
                    Cs[(size_t)(col >> 6) * N_NODES * SLICE_W + (size_t)row * SLICE_W + (col & 63)] = bf16_rne(v);
            }
            #pragma unroll
            for (int m = 1; m <= 8; m <<= 1) {
                pe += __shfl_xor(pe, m, 64);
                pr += __shfl_xor(pr, m, 64);
            }
            if (lr == 0 && row < M) {
                el[h * N_NODES + row] = pe;   // head-major planes
                er[h * N_NODES + row] = pr;
            }
        }
    }
}

// -------- CSR build --------
__global__ __launch_bounds__(256) void hist_kernel(const int* __restrict__ dst, int* __restrict__ count) {
    int e = blockIdx.x * 256 + threadIdx.x;
    if (e < N_EDGES) atomicAdd(&count[dst[e]], 1);
}

__global__ __launch_bounds__(256) void scan1_kernel(const int* __restrict__ counts,
                                                    int* __restrict__ offs,
                                                    int* __restrict__ bsums) {
    __shared__ int sh[256];
    int tid = threadIdx.x;
    int i = blockIdx.x * 256 + tid;
    int v = (i < N_NODES) ? counts[i] : 0;
    sh[tid] = v;
    __syncthreads();
    #pragma unroll
    for (int ofs = 1; ofs < 256; ofs <<= 1) {
        int t = (tid >= ofs) ? sh[tid - ofs] : 0;
        __syncthreads();
        sh[tid] += t;
        __syncthreads();
    }
    if (i < N_NODES) offs[i] = sh[tid] - v;
    if (tid == 255) bsums[blockIdx.x] = sh[255];
}

__global__ __launch_bounds__(256) void scan2_kernel(const int* __restrict__ bsums,
                                                    int* __restrict__ boffs, int nb) {
    __shared__ int sh[256];
    int tid = threadIdx.x;
    int v = (tid < nb) ? bsums[tid] : 0;
    sh[tid] = v;
    __syncthreads();
    #pragma unroll
    for (int ofs = 1; ofs < 256; ofs <<= 1) {
        int t = (tid >= ofs) ? sh[tid - ofs] : 0;
        __syncthreads();
        sh[tid] += t;
        __syncthreads();
    }
    if (tid < nb) boffs[tid] = sh[tid] - v;
}

// scan3: finalize offs AND init cursor
__global__ __launch_bounds__(256) void scan3_kernel(int* __restrict__ offs,
                                                    const int* __restrict__ boffs,
                                                    int* __restrict__ cursor) {
    int i = blockIdx.x * 256 + threadIdx.x;
    if (i < N_NODES) {
        int v = offs[i] + boffs[i >> 8];
        offs[i] = v;
        cursor[i] = v;
    }
    if (i == 0) offs[N_NODES] = N_EDGES;
}

// scatter: store src node id per slot
__global__ __launch_bounds__(256) void scatter_kernel(const int* __restrict__ src,
                                                      const int* __restrict__ dst,
                                                      int* __restrict__ cursor,
                                                      int* __restrict__ csrc) {
    int e = blockIdx.x * 256 + threadIdx.x;
    if (e >= N_EDGES) return;
    int p = atomicAdd(&cursor[dst[e]], 1);
    csrc[p] = src[e];
}

// ======== sliced aggregation v9: wave = 8 nodes x 1 HEAD-slice (128B granule) ========
// lane = (nn 0..7, fc 0..7): 8-lane group owns node nn's 128B slice row (fc = 16B chunk).
// Weight computed inline (uniform across the 8-lane group -> dsum per lane IS the exact
// denom, no reduce, no atomics). 8-deep NAMED unroll (no arrays -> no scratch).
// slice = blockIdx&3 -> XCD-pair pinned; 6.4MB/slice (L2-resident sweet spot).
// VGPR 52 / ILP beats occupancy here (r19); __expf beats exp2f (r20).
#define AGG9_EDGE(K)                                                                \
        int i##K = s0 + min(t + K, degc);                                           \
        int a##K = csrc[i##K];
#define AGG9_EL(K)                                                                  \
        float e##K = elh[a##K];
#define AGG9_Q(K)                                                                   \
        bf16x8 q##K = *(const bf16x8*)(basef + a##K * SLICE_W);
#define AGG9_W(K)                                                                   \
        float x##K = e##K + ern; x##K = fmaxf(x##K, NEG_SLOPE * x##K);              \
        float w##K = (t + K < deg) ? __expf(x##K) : 0.f;
#define AGG9_ACC(K)                                                                 \
        ac0 += w##K * bf2f((ushort)(q##K)[0]);                                      \
        ac1 += w##K * bf2f((ushort)(q##K)[1]);                                      \
        ac2 += w##K * bf2f((ushort)(q##K)[2]);                                      \
        ac3 += w##K * bf2f((ushort)(q##K)[3]);                                      \
        ac4 += w##K * bf2f((ushort)(q##K)[4]);                                      \
        ac5 += w##K * bf2f((ushort)(q##K)[5]);                                      \
        ac6 += w##K * bf2f((ushort)(q##K)[6]);                                      \
        ac7 += w##K * bf2f((ushort)(q##K)[7]);                                      \
        dsum += w##K;

#define AGG9_BODY()                                                                 \
    int b = blockIdx.x;                                                             \
    int slice = b & 3;                                                              \
    int wid = threadIdx.x >> 6;                                                     \
    int lane = threadIdx.x & 63;                                                    \
    int nn = lane >> 3;                                                             \
    int fc = lane & 7;                                                              \
    int h = slice;                                                                  \
    int n = (b >> 2) * 32 + wid * 8 + nn;                                           \
    int nc = min(n, N_NODES - 1);                                                   \
    const ushort* basef = fs + (size_t)slice * (N_NODES * SLICE_W) + fc * 8;        \
    const float* elh = el + (size_t)h * N_NODES;                                    \
    int s0 = offs[nc];                                                              \
    int deg = (n < N_NODES) ? (offs[nc + 1] - s0) : 0;                              \
    int degc = max(deg - 1, 0);                                                     \
    float ern = er[(size_t)h * N_NODES + nc];                                       \
    int md = deg;                                                                   \
    md = max(md, __shfl_xor(md, 8, 64));                                            \
    md = max(md, __shfl_xor(md, 16, 64));                                           \
    md = max(md, __shfl_xor(md, 32, 64));                                           \
    float ac0 = 0.f, ac1 = 0.f, ac2 = 0.f, ac3 = 0.f;                               \
    float ac4 = 0.f, ac5 = 0.f, ac6 = 0.f, ac7 = 0.f;                               \
    float dsum = 0.f;                                                               \
    for (int t = 0; t < md; t += 8) {                                               \
        AGG9_EDGE(0) AGG9_EDGE(1) AGG9_EDGE(2) AGG9_EDGE(3)                         \
        AGG9_EDGE(4) AGG9_EDGE(5) AGG9_EDGE(6) AGG9_EDGE(7)                         \
        AGG9_EL(0) AGG9_EL(1) AGG9_EL(2) AGG9_EL(3)                                 \
        AGG9_EL(4) AGG9_EL(5) AGG9_EL(6) AGG9_EL(7)                                 \
        AGG9_Q(0) AGG9_Q(1) AGG9_Q(2) AGG9_Q(3)                                     \
        AGG9_Q(4) AGG9_Q(5) AGG9_Q(6) AGG9_Q(7)                                     \
        AGG9_W(0) AGG9_W(1) AGG9_W(2) AGG9_W(3)                                     \
        AGG9_W(4) AGG9_W(5) AGG9_W(6) AGG9_W(7)                                     \
        AGG9_ACC(0) AGG9_ACC(1) AGG9_ACC(2) AGG9_ACC(3)                             \
        AGG9_ACC(4) AGG9_ACC(5) AGG9_ACC(6) AGG9_ACC(7)                             \
    }                                                                               \
    float inv = 1.f / fmaxf(dsum, 1e-9f);

// layer-0: write bf16 row-major hbuf (GEMM-1 A input)
__global__ __launch_bounds__(256) void agg9_l0(const ushort* __restrict__ fs,
                                               const int* __restrict__ csrc,
                                               const int* __restrict__ offs,
                                               const float* __restrict__ el,
                                               const float* __restrict__ er,
                                               ushort* __restrict__ hbuf) {
    AGG9_BODY()
    if (n < N_NODES) {
        ushort o[8] = {bf16_rne(elu_f(ac0 * inv)), bf16_rne(elu_f(ac1 * inv)),
                       bf16_rne(elu_f(ac2 * inv)), bf16_rne(elu_f(ac3 * inv)),
                       bf16_rne(elu_f(ac4 * inv)), bf16_rne(elu_f(ac5 * inv)),
                       bf16_rne(elu_f(ac6 * inv)), bf16_rne(elu_f(ac7 * inv))};
        *(bf16x8*)(hbuf + (size_t)n * NF + slice * SLICE_W + fc * 8) = *(bf16x8*)o;
    }
}

// final layer: write f32 heads into out[h][n][fc*8 .. fc*8+8)
__global__ __launch_bounds__(256) void agg9_final(const ushort* __restrict__ fs,
                                                  const int* __restrict__ csrc,
                                                  const int* __restrict__ offs,
                                                  const float* __restrict__ el,
                                                  const float* __restrict__ er,
                                                  float* __restrict__ out) {
    AGG9_BODY()
    if (n < N_NODES) {
        size_t p = (size_t)h * N_NODES * (ND + NC) + (size_t)n * (ND + NC) + fc * 8;
        *(float4*)(out + p)     = make_float4(elu_f(ac0 * inv), elu_f(ac1 * inv),
                                              elu_f(ac2 * inv), elu_f(ac3 * inv));
        *(float4*)(out + p + 4) = make_float4(elu_f(ac4 * inv), elu_f(ac5 * inv),
                                              elu_f(ac6 * inv), elu_f(ac7 * inv));
    }
}

// -------- cluster softmax v2: one logit per lane (h,c), Wc in LDS --------
__global__ __launch_bounds__(256) void cluster_kernel(const float* __restrict__ Wc,
                                                      const float* __restrict__ bc,
                                                      float* __restrict__ out) {
    __shared__ float WcS[ND * NC];   // 4 KB, [d][c]
    __shared__ float bcS[NC];
    int tid = threadIdx.x;
    #pragma unroll
    for (int i = 0; i < 4; ++i) WcS[i * 256 + tid] = Wc[i * 256 + tid];
    if (tid < NC) bcS[tid] = bc[tid];
    __syncthreads();
    int wid = tid >> 6;
    int lane = tid & 63;
    int h = lane >> 4, c = lane & 15;
    int n = blockIdx.x * 4 + wid;
    size_t base = (size_t)h * N_NODES * (ND + NC) + (size_t)n * (ND + NC);
    const float* hp = out + base;
    float acc = bcS[c];
    #pragma unroll
    for (int dd = 0; dd < 16; ++dd) {
        float4 f4 = *(const float4*)(hp + dd * 4);      // same addr across 16-lane group
        acc += f4.x * WcS[(dd * 4 + 0) * NC + c];
        acc += f4.y * WcS[(dd * 4 + 1) * NC + c];
        acc += f4.z * WcS[(dd * 4 + 2) * NC + c];
        acc += f4.w * WcS[(dd * 4 + 3) * NC + c];
    }
    float m = acc;
    m = fmaxf(m, __shfl_xor(m, 1, 64));
    m = fmaxf(m, __shfl_xor(m, 2, 64));
    m = fmaxf(m, __shfl_xor(m, 4, 64));
    m = fmaxf(m, __shfl_xor(m, 8, 64));
    float e = __expf(acc - m);
    float s = e;
    s += __shfl_xor(s, 1, 64);
    s += __shfl_xor(s, 2, 64);
    s += __shfl_xor(s, 4, 64);
    s += __shfl_xor(s, 8, 64);
    out[base + ND + c] = e / s;
}

extern "C" void kernel_launch(void* const* d_in, const int* in_sizes, int n_in,
                              void* d_out, int out_size, void* d_ws, size_t ws_size,
                              hipStream_t stream) {
    const float* x   = (const float*)d_in[0];
    const int* src   = (const int*)d_in[1];
    const int* dst   = (const int*)d_in[2];
    const float* W0  = (const float*)d_in[3];
    const float* al0 = (const float*)d_in[4];
    const float* ar0 = (const float*)d_in[5];
    const float* W1  = (const float*)d_in[6];
    const float* al1 = (const float*)d_in[7];
    const float* ar1 = (const float*)d_in[8];
    const float* Wc  = (const float*)d_in[9];
    const float* bc  = (const float*)d_in[10];
    float* out = (float*)d_out;

    char* ws = (char*)d_ws;
    size_t off = 0;
    auto alloc = [&](size_t bytes) { void* p = ws + off; off = (off + bytes + 255) & ~(size_t)255; return p; };
    ushort* featsl = (ushort*)alloc((size_t)N_NODES * NF * 2);   // 25.6 MB slice-major GEMM out
    ushort* xbf    = (ushort*)alloc((size_t)N_NODES * NF * 2);   // 25.6 MB
    ushort* hbuf   = (ushort*)alloc((size_t)N_NODES * NF * 2);   // 25.6 MB layer0 out (row-major)
    ushort* Wt0    = (ushort*)alloc((size_t)256 * 256 * 2);
    ushort* Wt1    = (ushort*)alloc((size_t)256 * 256 * 2);
    float*  el     = (float*)alloc((size_t)N_NODES * NH * 4);    // head-major planes
    float*  er     = (float*)alloc((size_t)N_NODES * NH * 4);
    int* counts    = (int*)alloc((size_t)N_NODES * 4);
    int* offs      = (int*)alloc((size_t)(N_NODES + 1) * 4);
    int* cursor    = (int*)alloc((size_t)N_NODES * 4);
    int* csrc      = (int*)alloc((size_t)N_EDGES * 4);
    int* bsums     = (int*)alloc(256 * 4);
    int* boffs     = (int*)alloc(256 * 4);

    const int EB = (N_EDGES + 255) / 256;          // 3125
    const int NB = (N_NODES + 255) / 256;          // 196
    const int GEMM_MB = (N_NODES + 127) / 128;     // 391
    const int C8 = (N_NODES * NF / 8 + 255) / 256;
    const int AGG_B = NSLICE * ((N_NODES + 31) / 32);  // 4 * 1563 = 6252 blocks

    // ---- CSR build ----
    hipMemsetAsync(counts, 0, (size_t)N_NODES * 4, stream);
    hist_kernel<<<EB, 256, 0, stream>>>(dst, counts);
    scan1_kernel<<<NB, 256, 0, stream>>>(counts, offs, bsums);
    scan2_kernel<<<1, 256, 0, stream>>>(bsums, boffs, NB);
    scan3_kernel<<<NB, 256, 0, stream>>>(offs, boffs, cursor);
    scatter_kernel<<<EB, 256, 0, stream>>>(src, dst, cursor, csrc);

    // ---- weight + input casts ----
    castWt_kernel<<<512, 256, 0, stream>>>(W0, W1, Wt0, Wt1);
    cast_bf16_kernel<<<C8, 256, 0, stream>>>(x, xbf, N_NODES * NF / 8);

    // ---- Layer 0 ----
    gemm_bf16<<<dim3(GEMM_MB, 2), 256, 0, stream>>>(xbf, Wt0, featsl, al0, ar0, el, er, N_NODES);
    agg9_l0<<<AGG_B, 256, 0, stream>>>(featsl, csrc, offs, el, er, hbuf);

    // ---- Layer 1 ----
    gemm_bf16<<<dim3(GEMM_MB, 2), 256, 0, stream>>>(hbuf, Wt1, featsl, al1, ar1, el, er, N_NODES);
    agg9_final<<<AGG_B, 256, 0, stream>>>(featsl, csrc, offs, el, er, out);

    // ---- cluster softmax ----
    cluster_kernel<<<N_NODES / 4, 256, 0, stream>>>(Wc, bc, out);
}